// Round 6
// baseline (135.250 us; speedup 1.0000x reference)
//
#include <hip/hip_runtime.h>
#include <hip/hip_bf16.h>

// Bi-attention, round 6: round-5 staged structure + (1) v_cvt_pk_bf16_f32
// P-packing (VALU diet), (2) vt fragments hoisted to chunk top (latency cover).

typedef __attribute__((ext_vector_type(8))) short s8v;   // 8 x bf16 frag
typedef __attribute__((ext_vector_type(4))) float f4v;   // 4 x f32 acc
typedef unsigned short ushort_t;
typedef unsigned int uint_t;

constexpr int B = 4, N = 4096, D = 64, SPLIT = 8, MCH = N / SPLIT;
constexpr int CH = 64, NST = MCH / CH;           // staged chunks per split
constexpr float C1 = 0.18033688011112042f;       // (1/8) * log2(e)

#define MFMA(A, Bv, C) __builtin_amdgcn_mfma_f32_16x16x32_bf16(A, Bv, C, 0, 0, 0)

__device__ __forceinline__ ushort_t f2bf(float x) {
    __hip_bfloat16 h = __float2bfloat16(x);
    return *reinterpret_cast<ushort_t*>(&h);
}

__device__ __forceinline__ uint_t cvtpk(float lo, float hi) {
    uint_t r;
    asm("v_cvt_pk_bf16_f32 %0, %1, %2" : "=v"(r) : "v"(lo), "v"(hi));
    return r;
}

// ---------------- projections (round-3 verbatim) ----------------
__global__ __launch_bounds__(256) void k_proj_x(const float* __restrict__ x,
        const float* __restrict__ w, const float* __restrict__ bias,
        ushort_t* __restrict__ qb, ushort_t* __restrict__ qt) {
    __shared__ float Xs[64][68];
    __shared__ float Ws[64][68];
    __shared__ float Bs[64];
    const int b = blockIdx.y, n0 = blockIdx.x * 64, t = threadIdx.x;
    const float* xp = x + ((size_t)b * N + n0) * D;
    for (int j = t; j < 4096; j += 256) Xs[j >> 6][j & 63] = xp[j];
    for (int j = t; j < 4096; j += 256) Ws[j >> 6][j & 63] = w[j];
    if (t < 64) Bs[t] = bias[t];
    __syncthreads();
    const int d = t & 63, grp = t >> 6;
    float wr[64];
#pragma unroll
    for (int k4 = 0; k4 < 16; ++k4) {
        float4 v = *reinterpret_cast<const float4*>(&Ws[d][k4 * 4]);
        wr[4 * k4 + 0] = v.x; wr[4 * k4 + 1] = v.y;
        wr[4 * k4 + 2] = v.z; wr[4 * k4 + 3] = v.w;
    }
    for (int i = 0; i < 16; ++i) {
        const int r = grp * 16 + i;
        float acc = Bs[d];
#pragma unroll
        for (int k4 = 0; k4 < 16; ++k4) {
            float4 xv = *reinterpret_cast<const float4*>(&Xs[r][k4 * 4]);
            acc += xv.x * wr[4 * k4] + xv.y * wr[4 * k4 + 1] +
                   xv.z * wr[4 * k4 + 2] + xv.w * wr[4 * k4 + 3];
        }
        qb[((size_t)b * N + n0 + r) * D + d] = f2bf(acc);
        qt[((size_t)b * D + d) * N + n0 + r] = f2bf(acc);
    }
}

__global__ __launch_bounds__(256) void k_proj_y(const float* __restrict__ y,
        const float* __restrict__ w, const float* __restrict__ bias,
        ushort_t* __restrict__ qb, ushort_t* __restrict__ qt) {
    __shared__ float Ys[64][68];
    __shared__ float Ws[64][68];
    __shared__ float Bs[64];
    const int b = blockIdx.y, m0 = blockIdx.x * 64, t = threadIdx.x;
    const float* yp = y + (size_t)b * D * N;
    for (int j = t; j < 4096; j += 256) {
        int k = j >> 6, mm = j & 63;
        Ys[mm][k] = yp[(size_t)k * N + m0 + mm];
    }
    for (int j = t; j < 4096; j += 256) Ws[j >> 6][j & 63] = w[j];
    if (t < 64) Bs[t] = bias[t];
    __syncthreads();
    const int d = t & 63, grp = t >> 6;
    float wr[64];
#pragma unroll
    for (int k4 = 0; k4 < 16; ++k4) {
        float4 v = *reinterpret_cast<const float4*>(&Ws[d][k4 * 4]);
        wr[4 * k4 + 0] = v.x; wr[4 * k4 + 1] = v.y;
        wr[4 * k4 + 2] = v.z; wr[4 * k4 + 3] = v.w;
    }
    for (int i = 0; i < 16; ++i) {
        const int r = grp * 16 + i;
        float acc = Bs[d];
#pragma unroll
        for (int k4 = 0; k4 < 16; ++k4) {
            float4 xv = *reinterpret_cast<const float4*>(&Ys[r][k4 * 4]);
            acc += xv.x * wr[4 * k4] + xv.y * wr[4 * k4 + 1] +
                   xv.z * wr[4 * k4 + 2] + xv.w * wr[4 * k4 + 3];
        }
        qb[((size_t)b * N + m0 + r) * D + d] = f2bf(acc);
        qt[((size_t)b * D + d) * N + m0 + r] = f2bf(acc);
    }
}

// ---------------- staged attention pass ----------------
template<bool WANT_SUM, bool OUT_DM>
__global__ __launch_bounds__(256, 4) void k_attn(
        const ushort_t* __restrict__ kbm,   // chunk-side rows  [B][N][D]
        const ushort_t* __restrict__ qbm,   // wave-side rows   [B][N][D]
        const ushort_t* __restrict__ vtm,   // PV B-side        [B][D][N]
        float* __restrict__ vout, float* __restrict__ ssump) {
    __shared__ ushort_t kbS[2][4096];       // 2 x 8KB staged chunk
    __shared__ ushort_t ptS[4][2][512];     // per-wave per-rt 16 x 32 P tile
    const int b = blockIdx.z, sp = blockIdx.y;
    const int tid = threadIdx.x;
    const int w = tid >> 6, lane = tid & 63, g = lane >> 4, c = lane & 15;
    const int xs = (blockIdx.x & 7) * 4 + (blockIdx.x >> 3);   // XCD-chunked
    const int wb = xs * 128 + w * 32;
    const int lo = sp * MCH;

    // round-3 P-tile addressing (proven)
    const int M = ((c >> 1) & 3) << 4;
    char* rowp0 = (char*)&ptS[w][0][0] + c * 64;
    char* rowp1 = (char*)&ptS[w][1][0] + c * 64;
    const int wo0 = (8 * g) ^ M, wo1 = (32 + 8 * g) ^ M;
    const int ro  = (16 * g) ^ M;

    // kb-tile read swizzle: row = 32*sub + 16*h + c  ->  row&7 == c&7
    const int swzc = (c & 7) << 4;

    s8v a[2][2];
#pragma unroll
    for (int rt = 0; rt < 2; ++rt) {
        const ushort_t* p = qbm + ((size_t)b * N + wb + rt * 16 + c) * D + 8 * g;
        a[rt][0] = *reinterpret_cast<const s8v*>(p);
        a[rt][1] = *reinterpret_cast<const s8v*>(p + 32);
    }

    // staging: thread owns logical 16B chunks s0, s0+4096 of the 8KB tile
    const int s0 = tid * 16, s1 = s0 + 4096;
    const int p0 = s0 ^ (((s0 >> 7) & 7) << 4);
    const int p1 = s1 ^ (((s1 >> 7) & 7) << 4);
    const char* gkb = (const char*)(kbm + ((size_t)b * N + lo) * D);
    char* kb0 = (char*)&kbS[0][0];
    char* kb1 = (char*)&kbS[1][0];
    const ushort_t* vbase = vtm + ((size_t)b * D + c) * N + 8 * g;

    f4v accO[2][4] = {};
    float rs0 = 0.f, rs1 = 0.f;
    s8v kb[2][2], pa0, pa1;

#define LDKB_LDS(KC, SUB)                                                     \
    {                                                                         \
        const char* _r0 = (KC) + (32 * (SUB) + c) * 128;                      \
        kb[0][0] = *reinterpret_cast<const s8v*>(_r0 + ((16 * g) ^ swzc));    \
        kb[0][1] = *reinterpret_cast<const s8v*>(_r0 + ((64 + 16 * g) ^ swzc)); \
        kb[1][0] = *reinterpret_cast<const s8v*>(_r0 + 2048 + ((16 * g) ^ swzc)); \
        kb[1][1] = *reinterpret_cast<const s8v*>(_r0 + 2048 + ((64 + 16 * g) ^ swzc)); \
    }
#define QKEXP(PQ)                                                             \
    f4v PQ[2][2] = {};                                                        \
    __builtin_amdgcn_s_setprio(1);                                            \
    _Pragma("unroll")                                                         \
    for (int rt = 0; rt < 2; ++rt) {                                          \
        _Pragma("unroll")                                                     \
        for (int h = 0; h < 2; ++h) {                                         \
            PQ[rt][h] = MFMA(kb[h][0], a[rt][0], PQ[rt][h]);                  \
            PQ[rt][h] = MFMA(kb[h][1], a[rt][1], PQ[rt][h]);                  \
        }                                                                     \
    }                                                                         \
    __builtin_amdgcn_s_setprio(0);
#define PACKWRITE(PQ)                                                         \
    {                                                                         \
        _Pragma("unroll")                                                     \
        for (int rt = 0; rt < 2; ++rt) {                                      \
            char* rp = rt ? rowp1 : rowp0;                                    \
            float rsl = 0.f;                                                  \
            _Pragma("unroll")                                                 \
            for (int h = 0; h < 2; ++h) {                                     \
                float e0 = exp2f(PQ[rt][h][0] * C1);                          \
                float e1 = exp2f(PQ[rt][h][1] * C1);                          \
                float e2 = exp2f(PQ[rt][h][2] * C1);                          \
                float e3 = exp2f(PQ[rt][h][3] * C1);                          \
                if (WANT_SUM) rsl += (e0 + e1) + (e2 + e3);                   \
                uint2 pk = make_uint2(cvtpk(e0, e1), cvtpk(e2, e3));          \
                *reinterpret_cast<uint2*>(rp + (h ? wo1 : wo0)) = pk;         \
            }                                                                 \
            if (WANT_SUM) { if (rt) rs1 += rsl; else rs0 += rsl; }            \
        }                                                                     \
    }
#define PV(VT)                                                                \
    __builtin_amdgcn_s_setprio(1);                                            \
    _Pragma("unroll")                                                         \
    for (int dc = 0; dc < 4; ++dc) {                                          \
        accO[0][dc] = MFMA(pa0, (VT)[dc], accO[0][dc]);                       \
        accO[1][dc] = MFMA(pa1, (VT)[dc], accO[1][dc]);                       \
    }                                                                         \
    __builtin_amdgcn_s_setprio(0);
#define RDTILE()                                                              \
    pa0 = *reinterpret_cast<const s8v*>(rowp0 + ro);                          \
    pa1 = *reinterpret_cast<const s8v*>(rowp1 + ro);
#define SUBCHUNK(KC, SUB, VT)                                                 \
    {                                                                         \
        LDKB_LDS(KC, SUB)                                                     \
        QKEXP(pq)                                                             \
        PACKWRITE(pq)                                                         \
        asm volatile("s_waitcnt lgkmcnt(0)" ::: "memory");                    \
        RDTILE()                                                              \
        PV(VT)                                                                \
    }

    // prologue: stage chunk 0 into kb0
    {
        uint4 t0 = *reinterpret_cast<const uint4*>(gkb + s0);
        uint4 t1 = *reinterpret_cast<const uint4*>(gkb + s1);
        *reinterpret_cast<uint4*>(kb0 + p0) = t0;
        *reinterpret_cast<uint4*>(kb0 + p1) = t1;
    }
    __syncthreads();

    for (int i = 0; i < NST; ++i) {
        char* kcur = (i & 1) ? kb1 : kb0;
        char* knxt = (i & 1) ? kb0 : kb1;
        // issue next-chunk stage loads (wraps harmlessly to 0 at the end)
        const char* gn = gkb + (((i + 1) & (NST - 1)) * (CH * D * 2));
        uint4 t0 = *reinterpret_cast<const uint4*>(gn + s0);
        uint4 t1 = *reinterpret_cast<const uint4*>(gn + s1);

        const int m0 = lo + i * CH;
        // hoisted vt fragments for both subchunks (L2 latency covered by QK/exp)
        s8v vtA[4], vtB[4];
#pragma unroll
        for (int dc = 0; dc < 4; ++dc) {
            vtA[dc] = *reinterpret_cast<const s8v*>(vbase + (size_t)dc * 16 * N + m0);
            vtB[dc] = *reinterpret_cast<const s8v*>(vbase + (size_t)dc * 16 * N + m0 + 32);
        }

        SUBCHUNK(kcur, 0, vtA)
        SUBCHUNK(kcur, 1, vtB)

        // land the stage, hand off buffers
        *reinterpret_cast<uint4*>(knxt + p0) = t0;
        *reinterpret_cast<uint4*>(knxt + p1) = t1;
        __syncthreads();
    }

#undef LDKB_LDS
#undef QKEXP
#undef PACKWRITE
#undef PV
#undef RDTILE
#undef SUBCHUNK

    const size_t ob = ((size_t)sp * B + b) * N;
    if (OUT_DM) {
#pragma unroll
        for (int rt = 0; rt < 2; ++rt)
#pragma unroll
            for (int dc = 0; dc < 4; ++dc) {
                size_t base = (((size_t)sp * B + b) * D + 16 * dc + c) * N
                              + wb + 16 * rt + 4 * g;
                *reinterpret_cast<f4v*>(&vout[base]) = accO[rt][dc];
            }
    } else {
#pragma unroll
        for (int rt = 0; rt < 2; ++rt)
#pragma unroll
            for (int dc = 0; dc < 4; ++dc)
#pragma unroll
                for (int r = 0; r < 4; ++r)
                    vout[(ob + wb + 16 * rt + 4 * g + r) * D + 16 * dc + c] =
                        accO[rt][dc][r];
    }
    if (WANT_SUM) {
        rs0 += __shfl_xor(rs0, 16); rs0 += __shfl_xor(rs0, 32);
        rs1 += __shfl_xor(rs1, 16); rs1 += __shfl_xor(rs1, 32);
        if (g == 0) {
            ssump[ob + wb + c] = rs0;
            ssump[ob + wb + 16 + c] = rs1;
        }
    }
}

// combine v2 partials: out = sum(acc)/sum(S); emit sinv[n]=1/S for pass 2
__global__ __launch_bounds__(256) void k_comb_v2(const float* __restrict__ v2p,
        const float* __restrict__ ssump, float* __restrict__ out,
        float* __restrict__ sinv) {
    const int t = blockIdx.x * 256 + threadIdx.x;   // over B*N*16
    const int bn = t >> 4, d0 = (t & 15) * 4;
    float S = 0.f;
#pragma unroll
    for (int s = 0; s < SPLIT; ++s) S += ssump[(size_t)s * B * N + bn];
    const float inv = 1.0f / S;
    f4v acc = {};
#pragma unroll
    for (int s = 0; s < SPLIT; ++s)
        acc += *reinterpret_cast<const f4v*>(&v2p[((size_t)s * B * N + bn) * D + d0]);
    acc *= inv;
    *reinterpret_cast<f4v*>(&out[(size_t)bn * D + d0]) = acc;
    if (d0 == 0) sinv[bn] = inv;
}

// q1s_t[d][n] = q1t[d][n] * sinv[n]   (bf16, PV B-side for pass 2)
__global__ __launch_bounds__(256) void k_scale(const ushort_t* __restrict__ q1t,
        const float* __restrict__ sinv, ushort_t* __restrict__ q1s) {
    const size_t t = ((size_t)blockIdx.x * 256 + threadIdx.x) * 8;  // over B*D*N
    const int b = (int)(t / ((size_t)D * N));
    const int n0 = (int)(t % N);
    s8v v = *reinterpret_cast<const s8v*>(q1t + t);
    const float* sv = sinv + (size_t)b * N + n0;
    s8v o;
#pragma unroll
    for (int j = 0; j < 8; ++j) {
        uint_t u = ((uint_t)(ushort_t)v[j]) << 16;
        float f = __uint_as_float(u) * sv[j];
        o[j] = (short)f2bf(f);
    }
    *reinterpret_cast<s8v*>(q1s + t) = o;
}

__global__ __launch_bounds__(256) void k_comb_v1(const float* __restrict__ v1p,
        float* __restrict__ out2) {
    const size_t t = ((size_t)blockIdx.x * 256 + threadIdx.x) * 4;   // over B*D*N
    f4v acc = {};
#pragma unroll
    for (int s = 0; s < SPLIT; ++s)
        acc += *reinterpret_cast<const f4v*>(&v1p[(size_t)s * B * D * N + t]);
    *reinterpret_cast<f4v*>(&out2[t]) = acc;
}

extern "C" void kernel_launch(void* const* d_in, const int* in_sizes, int n_in,
                              void* d_out, int out_size, void* d_ws, size_t ws_size,
                              hipStream_t stream) {
    const float* x  = (const float*)d_in[0];
    const float* y  = (const float*)d_in[1];
    const float* w1 = (const float*)d_in[2];
    const float* b1 = (const float*)d_in[3];
    const float* w2 = (const float*)d_in[4];
    const float* b2 = (const float*)d_in[5];
    float* out = (float*)d_out;

    char* ws = (char*)d_ws;
    const size_t QE = (size_t)B * N * D;
    ushort_t* q1b = (ushort_t*)ws;
    ushort_t* q2b = q1b + QE;
    ushort_t* q1t = q2b + QE;
    ushort_t* q2t = q1t + QE;
    ushort_t* q1s = q2t + QE;
    float* fb   = (float*)(ws + QE * 5 * sizeof(ushort_t));
    float* sinv = fb;                                   // B*N
    float* ssum = sinv + (size_t)B * N;                 // SPLIT*B*N
    float* vpart = ssum + (size_t)SPLIT * B * N;        // SPLIT*QE (shared)

    dim3 blk(256);
    k_proj_x<<<dim3(N / 64, B), blk, 0, stream>>>(x, w1, b1, q1b, q1t);
    k_proj_y<<<dim3(N / 64, B), blk, 0, stream>>>(y, w2, b2, q2b, q2t);
    // pass 1: chunk=q2 rows (m), wave=q1 rows (n), PV B = q2t -> v2 partials
    k_attn<true, false><<<dim3(N / 128, SPLIT, B), blk, 0, stream>>>(
        q2b, q1b, q2t, vpart, ssum);
    k_comb_v2<<<dim3(B * N * 16 / 256), blk, 0, stream>>>(vpart, ssum, out, sinv);
    k_scale<<<dim3((int)(QE / 8 / 256)), blk, 0, stream>>>(q1t, sinv, q1s);
    // pass 2: chunk=q1 rows (n), wave=q2 rows (m), PV B = scaled q1t -> v1 partials
    k_attn<false, true><<<dim3(N / 128, SPLIT, B), blk, 0, stream>>>(
        q1b, q2b, q1s, vpart, nullptr);
    k_comb_v1<<<dim3((int)(QE / 4 / 256)), blk, 0, stream>>>(vpart, out + QE);
}

// Round 7
// 116.545 us; speedup vs baseline: 1.1605x; 1.1605x over previous
//
#include <hip/hip_runtime.h>
#include <hip/hip_bf16.h>

// Bi-attention, round 7: round-5 staged k_attn (proven 45.3us) with
// (1) packed bf16 cast via __float22bfloat162_rn builtin (no inline asm),
// (2) bf16 partials for vpart (halves partial HBM traffic).

typedef __attribute__((ext_vector_type(8))) short s8v;   // 8 x bf16 frag
typedef __attribute__((ext_vector_type(4))) float f4v;   // 4 x f32 acc
typedef unsigned short ushort_t;
typedef unsigned int uint_t;

constexpr int B = 4, N = 4096, D = 64, SPLIT = 8, MCH = N / SPLIT;
constexpr int CH = 64, NST = MCH / CH;           // staged chunks per split
constexpr float C1 = 0.18033688011112042f;       // (1/8) * log2(e)

#define MFMA(A, Bv, C) __builtin_amdgcn_mfma_f32_16x16x32_bf16(A, Bv, C, 0, 0, 0)

__device__ __forceinline__ ushort_t f2bf(float x) {
    __hip_bfloat16 h = __float2bfloat16(x);
    return *reinterpret_cast<ushort_t*>(&h);
}

// packed RNE pair-cast via builtin (compiler may select v_cvt_pk_bf16_f32)
__device__ __forceinline__ uint_t pk2(float lo, float hi) {
    __hip_bfloat162 h = __float22bfloat162_rn(make_float2(lo, hi));
    return *reinterpret_cast<uint_t*>(&h);
}

__device__ __forceinline__ float bf2f(ushort_t u) {
    return __uint_as_float(((uint_t)u) << 16);
}

// ---------------- projections (round-3 verbatim) ----------------
__global__ __launch_bounds__(256) void k_proj_x(const float* __restrict__ x,
        const float* __restrict__ w, const float* __restrict__ bias,
        ushort_t* __restrict__ qb, ushort_t* __restrict__ qt) {
    __shared__ float Xs[64][68];
    __shared__ float Ws[64][68];
    __shared__ float Bs[64];
    const int b = blockIdx.y, n0 = blockIdx.x * 64, t = threadIdx.x;
    const float* xp = x + ((size_t)b * N + n0) * D;
    for (int j = t; j < 4096; j += 256) Xs[j >> 6][j & 63] = xp[j];
    for (int j = t; j < 4096; j += 256) Ws[j >> 6][j & 63] = w[j];
    if (t < 64) Bs[t] = bias[t];
    __syncthreads();
    const int d = t & 63, grp = t >> 6;
    float wr[64];
#pragma unroll
    for (int k4 = 0; k4 < 16; ++k4) {
        float4 v = *reinterpret_cast<const float4*>(&Ws[d][k4 * 4]);
        wr[4 * k4 + 0] = v.x; wr[4 * k4 + 1] = v.y;
        wr[4 * k4 + 2] = v.z; wr[4 * k4 + 3] = v.w;
    }
    for (int i = 0; i < 16; ++i) {
        const int r = grp * 16 + i;
        float acc = Bs[d];
#pragma unroll
        for (int k4 = 0; k4 < 16; ++k4) {
            float4 xv = *reinterpret_cast<const float4*>(&Xs[r][k4 * 4]);
            acc += xv.x * wr[4 * k4] + xv.y * wr[4 * k4 + 1] +
                   xv.z * wr[4 * k4 + 2] + xv.w * wr[4 * k4 + 3];
        }
        qb[((size_t)b * N + n0 + r) * D + d] = f2bf(acc);
        qt[((size_t)b * D + d) * N + n0 + r] = f2bf(acc);
    }
}

__global__ __launch_bounds__(256) void k_proj_y(const float* __restrict__ y,
        const float* __restrict__ w, const float* __restrict__ bias,
        ushort_t* __restrict__ qb, ushort_t* __restrict__ qt) {
    __shared__ float Ys[64][68];
    __shared__ float Ws[64][68];
    __shared__ float Bs[64];
    const int b = blockIdx.y, m0 = blockIdx.x * 64, t = threadIdx.x;
    const float* yp = y + (size_t)b * D * N;
    for (int j = t; j < 4096; j += 256) {
        int k = j >> 6, mm = j & 63;
        Ys[mm][k] = yp[(size_t)k * N + m0 + mm];
    }
    for (int j = t; j < 4096; j += 256) Ws[j >> 6][j & 63] = w[j];
    if (t < 64) Bs[t] = bias[t];
    __syncthreads();
    const int d = t & 63, grp = t >> 6;
    float wr[64];
#pragma unroll
    for (int k4 = 0; k4 < 16; ++k4) {
        float4 v = *reinterpret_cast<const float4*>(&Ws[d][k4 * 4]);
        wr[4 * k4 + 0] = v.x; wr[4 * k4 + 1] = v.y;
        wr[4 * k4 + 2] = v.z; wr[4 * k4 + 3] = v.w;
    }
    for (int i = 0; i < 16; ++i) {
        const int r = grp * 16 + i;
        float acc = Bs[d];
#pragma unroll
        for (int k4 = 0; k4 < 16; ++k4) {
            float4 xv = *reinterpret_cast<const float4*>(&Ys[r][k4 * 4]);
            acc += xv.x * wr[4 * k4] + xv.y * wr[4 * k4 + 1] +
                   xv.z * wr[4 * k4 + 2] + xv.w * wr[4 * k4 + 3];
        }
        qb[((size_t)b * N + m0 + r) * D + d] = f2bf(acc);
        qt[((size_t)b * D + d) * N + m0 + r] = f2bf(acc);
    }
}

// ---------------- staged attention pass (round-5 structure) ----------------
template<bool WANT_SUM, bool OUT_DM>
__global__ __launch_bounds__(256, 4) void k_attn(
        const ushort_t* __restrict__ kbm,   // chunk-side rows  [B][N][D]
        const ushort_t* __restrict__ qbm,   // wave-side rows   [B][N][D]
        const ushort_t* __restrict__ vtm,   // PV B-side        [B][D][N]
        ushort_t* __restrict__ vout, float* __restrict__ ssump) {
    __shared__ ushort_t kbS[2][4096];       // 2 x 8KB staged chunk
    __shared__ ushort_t ptS[4][2][512];     // per-wave per-rt 16 x 32 P tile
    const int b = blockIdx.z, sp = blockIdx.y;
    const int tid = threadIdx.x;
    const int w = tid >> 6, lane = tid & 63, g = lane >> 4, c = lane & 15;
    const int xs = (blockIdx.x & 7) * 4 + (blockIdx.x >> 3);   // XCD-chunked
    const int wb = xs * 128 + w * 32;
    const int lo = sp * MCH;

    // round-3 P-tile addressing (proven)
    const int M = ((c >> 1) & 3) << 4;
    char* rowp0 = (char*)&ptS[w][0][0] + c * 64;
    char* rowp1 = (char*)&ptS[w][1][0] + c * 64;
    const int wo0 = (8 * g) ^ M, wo1 = (32 + 8 * g) ^ M;
    const int ro  = (16 * g) ^ M;

    // kb-tile read swizzle: row = 32*sub + 16*h + c  ->  row&7 == c&7
    const int swzc = (c & 7) << 4;

    s8v a[2][2];
#pragma unroll
    for (int rt = 0; rt < 2; ++rt) {
        const ushort_t* p = qbm + ((size_t)b * N + wb + rt * 16 + c) * D + 8 * g;
        a[rt][0] = *reinterpret_cast<const s8v*>(p);
        a[rt][1] = *reinterpret_cast<const s8v*>(p + 32);
    }

    // staging: thread owns logical 16B chunks s0, s0+4096 of the 8KB tile
    const int s0 = tid * 16, s1 = s0 + 4096;
    const int p0 = s0 ^ (((s0 >> 7) & 7) << 4);
    const int p1 = s1 ^ (((s1 >> 7) & 7) << 4);
    const char* gkb = (const char*)(kbm + ((size_t)b * N + lo) * D);
    char* kb0 = (char*)&kbS[0][0];
    char* kb1 = (char*)&kbS[1][0];
    const ushort_t* vbase = vtm + ((size_t)b * D + c) * N + 8 * g;

    f4v accO[2][4] = {};
    float rs0 = 0.f, rs1 = 0.f;
    s8v kb[2][2], vt[4], pa0, pa1;

#define LDKB_LDS(KC, SUB)                                                     \
    {                                                                         \
        const char* _r0 = (KC) + (32 * (SUB) + c) * 128;                      \
        kb[0][0] = *reinterpret_cast<const s8v*>(_r0 + ((16 * g) ^ swzc));    \
        kb[0][1] = *reinterpret_cast<const s8v*>(_r0 + ((64 + 16 * g) ^ swzc)); \
        kb[1][0] = *reinterpret_cast<const s8v*>(_r0 + 2048 + ((16 * g) ^ swzc)); \
        kb[1][1] = *reinterpret_cast<const s8v*>(_r0 + 2048 + ((64 + 16 * g) ^ swzc)); \
    }
#define LDVT(P)                                                               \
    {                                                                         \
        _Pragma("unroll")                                                     \
        for (int dc = 0; dc < 4; ++dc)                                        \
            vt[dc] = *reinterpret_cast<const s8v*>(vbase + (size_t)dc * 16 * N + (P)); \
    }
#define QKEXP(PQ)                                                             \
    f4v PQ[2][2] = {};                                                        \
    __builtin_amdgcn_s_setprio(1);                                            \
    _Pragma("unroll")                                                         \
    for (int rt = 0; rt < 2; ++rt) {                                          \
        _Pragma("unroll")                                                     \
        for (int h = 0; h < 2; ++h) {                                         \
            PQ[rt][h] = MFMA(kb[h][0], a[rt][0], PQ[rt][h]);                  \
            PQ[rt][h] = MFMA(kb[h][1], a[rt][1], PQ[rt][h]);                  \
        }                                                                     \
    }                                                                         \
    __builtin_amdgcn_s_setprio(0);
#define PACKWRITE(PQ)                                                         \
    {                                                                         \
        _Pragma("unroll")                                                     \
        for (int rt = 0; rt < 2; ++rt) {                                      \
            char* rp = rt ? rowp1 : rowp0;                                    \
            float rsl = 0.f;                                                  \
            _Pragma("unroll")                                                 \
            for (int h = 0; h < 2; ++h) {                                     \
                float e0 = exp2f(PQ[rt][h][0] * C1);                          \
                float e1 = exp2f(PQ[rt][h][1] * C1);                          \
                float e2 = exp2f(PQ[rt][h][2] * C1);                          \
                float e3 = exp2f(PQ[rt][h][3] * C1);                          \
                if (WANT_SUM) rsl += (e0 + e1) + (e2 + e3);                   \
                uint2 pk = make_uint2(pk2(e0, e1), pk2(e2, e3));              \
                *reinterpret_cast<uint2*>(rp + (h ? wo1 : wo0)) = pk;         \
            }                                                                 \
            if (WANT_SUM) { if (rt) rs1 += rsl; else rs0 += rsl; }            \
        }                                                                     \
    }
#define PV()                                                                  \
    __builtin_amdgcn_s_setprio(1);                                            \
    _Pragma("unroll")                                                         \
    for (int dc = 0; dc < 4; ++dc) {                                          \
        accO[0][dc] = MFMA(pa0, vt[dc], accO[0][dc]);                         \
        accO[1][dc] = MFMA(pa1, vt[dc], accO[1][dc]);                         \
    }                                                                         \
    __builtin_amdgcn_s_setprio(0);
#define RDTILE()                                                              \
    pa0 = *reinterpret_cast<const s8v*>(rowp0 + ro);                          \
    pa1 = *reinterpret_cast<const s8v*>(rowp1 + ro);
#define SUBCHUNK(KC, SUB, M0)                                                 \
    {                                                                         \
        LDKB_LDS(KC, SUB)                                                     \
        QKEXP(pq)                                                             \
        PACKWRITE(pq)                                                         \
        LDVT(M0)                                                              \
        asm volatile("s_waitcnt lgkmcnt(0)" ::: "memory");                    \
        RDTILE()                                                              \
        PV()                                                                  \
    }

    // prologue: stage chunk 0 into kb0
    {
        uint4 t0 = *reinterpret_cast<const uint4*>(gkb + s0);
        uint4 t1 = *reinterpret_cast<const uint4*>(gkb + s1);
        *reinterpret_cast<uint4*>(kb0 + p0) = t0;
        *reinterpret_cast<uint4*>(kb0 + p1) = t1;
    }
    __syncthreads();

    for (int i = 0; i < NST; ++i) {
        char* kcur = (i & 1) ? kb1 : kb0;
        char* knxt = (i & 1) ? kb0 : kb1;
        // issue next-chunk stage loads (wraps harmlessly to 0 at the end)
        const char* gn = gkb + (((i + 1) & (NST - 1)) * (CH * D * 2));
        uint4 t0 = *reinterpret_cast<const uint4*>(gn + s0);
        uint4 t1 = *reinterpret_cast<const uint4*>(gn + s1);

        const int m0 = lo + i * CH;
        SUBCHUNK(kcur, 0, m0)
        SUBCHUNK(kcur, 1, m0 + 32)

        // land the stage, hand off buffers
        *reinterpret_cast<uint4*>(knxt + p0) = t0;
        *reinterpret_cast<uint4*>(knxt + p1) = t1;
        __syncthreads();
    }

#undef LDKB_LDS
#undef LDVT
#undef QKEXP
#undef PACKWRITE
#undef PV
#undef RDTILE
#undef SUBCHUNK

    const size_t ob = ((size_t)sp * B + b) * N;
    if (OUT_DM) {
        // [sp][b][d][m] bf16, lane's 4 acc entries are consecutive m
#pragma unroll
        for (int rt = 0; rt < 2; ++rt)
#pragma unroll
            for (int dc = 0; dc < 4; ++dc) {
                size_t base = (((size_t)sp * B + b) * D + 16 * dc + c) * N
                              + wb + 16 * rt + 4 * g;
                uint2 pk = make_uint2(pk2(accO[rt][dc][0], accO[rt][dc][1]),
                                      pk2(accO[rt][dc][2], accO[rt][dc][3]));
                *reinterpret_cast<uint2*>(&vout[base]) = pk;
            }
    } else {
#pragma unroll
        for (int rt = 0; rt < 2; ++rt)
#pragma unroll
            for (int dc = 0; dc < 4; ++dc)
#pragma unroll
                for (int r = 0; r < 4; ++r)
                    vout[(ob + wb + 16 * rt + 4 * g + r) * D + 16 * dc + c] =
                        f2bf(accO[rt][dc][r]);
    }
    if (WANT_SUM) {
        rs0 += __shfl_xor(rs0, 16); rs0 += __shfl_xor(rs0, 32);
        rs1 += __shfl_xor(rs1, 16); rs1 += __shfl_xor(rs1, 32);
        if (g == 0) {
            ssump[ob + wb + c] = rs0;
            ssump[ob + wb + 16 + c] = rs1;
        }
    }
}

// combine v2 partials (bf16): out = sum(acc)/sum(S); emit sinv[n]=1/S
__global__ __launch_bounds__(256) void k_comb_v2(const ushort_t* __restrict__ v2p,
        const float* __restrict__ ssump, float* __restrict__ out,
        float* __restrict__ sinv) {
    const int t = blockIdx.x * 256 + threadIdx.x;   // over B*N*16
    const int bn = t >> 4, d0 = (t & 15) * 4;
    float S = 0.f;
#pragma unroll
    for (int s = 0; s < SPLIT; ++s) S += ssump[(size_t)s * B * N + bn];
    const float inv = 1.0f / S;
    f4v acc = {};
#pragma unroll
    for (int s = 0; s < SPLIT; ++s) {
        uint2 u = *reinterpret_cast<const uint2*>(
            &v2p[((size_t)s * B * N + bn) * D + d0]);
        acc[0] += bf2f((ushort_t)(u.x & 0xffff));
        acc[1] += bf2f((ushort_t)(u.x >> 16));
        acc[2] += bf2f((ushort_t)(u.y & 0xffff));
        acc[3] += bf2f((ushort_t)(u.y >> 16));
    }
    acc *= inv;
    *reinterpret_cast<f4v*>(&out[(size_t)bn * D + d0]) = acc;
    if (d0 == 0) sinv[bn] = inv;
}

// q1s_t[d][n] = q1t[d][n] * sinv[n]   (bf16, PV B-side for pass 2)
__global__ __launch_bounds__(256) void k_scale(const ushort_t* __restrict__ q1t,
        const float* __restrict__ sinv, ushort_t* __restrict__ q1s) {
    const size_t t = ((size_t)blockIdx.x * 256 + threadIdx.x) * 8;  // over B*D*N
    const int b = (int)(t / ((size_t)D * N));
    const int n0 = (int)(t % N);
    s8v v = *reinterpret_cast<const s8v*>(q1t + t);
    const float* sv = sinv + (size_t)b * N + n0;
    s8v o;
#pragma unroll
    for (int j = 0; j < 8; ++j) {
        uint_t u = ((uint_t)(ushort_t)v[j]) << 16;
        float f = __uint_as_float(u) * sv[j];
        o[j] = (short)f2bf(f);
    }
    *reinterpret_cast<s8v*>(q1s + t) = o;
}

__global__ __launch_bounds__(256) void k_comb_v1(const ushort_t* __restrict__ v1p,
        float* __restrict__ out2) {
    const size_t t = ((size_t)blockIdx.x * 256 + threadIdx.x) * 4;   // over B*D*N
    f4v acc = {};
#pragma unroll
    for (int s = 0; s < SPLIT; ++s) {
        uint2 u = *reinterpret_cast<const uint2*>(&v1p[(size_t)s * B * D * N + t]);
        acc[0] += bf2f((ushort_t)(u.x & 0xffff));
        acc[1] += bf2f((ushort_t)(u.x >> 16));
        acc[2] += bf2f((ushort_t)(u.y & 0xffff));
        acc[3] += bf2f((ushort_t)(u.y >> 16));
    }
    *reinterpret_cast<f4v*>(&out2[t]) = acc;
}

extern "C" void kernel_launch(void* const* d_in, const int* in_sizes, int n_in,
                              void* d_out, int out_size, void* d_ws, size_t ws_size,
                              hipStream_t stream) {
    const float* x  = (const float*)d_in[0];
    const float* y  = (const float*)d_in[1];
    const float* w1 = (const float*)d_in[2];
    const float* b1 = (const float*)d_in[3];
    const float* w2 = (const float*)d_in[4];
    const float* b2 = (const float*)d_in[5];
    float* out = (float*)d_out;

    char* ws = (char*)d_ws;
    const size_t QE = (size_t)B * N * D;
    ushort_t* q1b = (ushort_t*)ws;
    ushort_t* q2b = q1b + QE;
    ushort_t* q1t = q2b + QE;
    ushort_t* q2t = q1t + QE;
    ushort_t* q1s = q2t + QE;
    float* fb   = (float*)(ws + QE * 5 * sizeof(ushort_t));
    float* sinv = fb;                                   // B*N
    float* ssum = sinv + (size_t)B * N;                 // SPLIT*B*N
    ushort_t* vpart = (ushort_t*)(ssum + (size_t)SPLIT * B * N);  // SPLIT*QE bf16

    dim3 blk(256);
    k_proj_x<<<dim3(N / 64, B), blk, 0, stream>>>(x, w1, b1, q1b, q1t);
    k_proj_y<<<dim3(N / 64, B), blk, 0, stream>>>(y, w2, b2, q2b, q2t);
    // pass 1: chunk=q2 rows (m), wave=q1 rows (n), PV B = q2t -> v2 partials
    k_attn<true, false><<<dim3(N / 128, SPLIT, B), blk, 0, stream>>>(
        q2b, q1b, q2t, vpart, ssum);
    k_comb_v2<<<dim3(B * N * 16 / 256), blk, 0, stream>>>(vpart, ssum, out, sinv);
    k_scale<<<dim3((int)(QE / 8 / 256)), blk, 0, stream>>>(q1t, sinv, q1s);
    // pass 2: chunk=q1 rows (n), wave=q2 rows (m), PV B = scaled q1t -> v1 partials
    k_attn<false, true><<<dim3(N / 128, SPLIT, B), blk, 0, stream>>>(
        q1b, q2b, q1s, vpart, nullptr);
    k_comb_v1<<<dim3((int)(QE / 4 / 256)), blk, 0, stream>>>(vpart, out + QE);
}